// Round 6
// baseline (160.290 us; speedup 1.0000x reference)
//
#include <hip/hip_runtime.h>
#include <math.h>

// B=2, L=1024, D=1024, H=16, HD=64.
// probs_ij = s_ij*nc_j^-0.5 / sum_j(s_ij*nc_j^-0.5)   (N_R^-0.5 cancels)
// s_ij = (1 + dist_ij/64)^(-65.5), dist from bf16-rounded Q,K.

typedef __attribute__((ext_vector_type(8))) short short8;
typedef __attribute__((ext_vector_type(4))) float f32x4;

__device__ inline unsigned short f2bf(float f) {
  unsigned int u = __float_as_uint(f);
  unsigned int r = (u + 0x7FFFu + ((u >> 16) & 1u)) >> 16;
  return (unsigned short)r;
}
__device__ inline float bf2f(unsigned short s) {
  return __uint_as_float(((unsigned int)s) << 16);
}
// pack two f32 -> one dword of 2 bf16 (RNE), lo = first arg
__device__ inline unsigned int cvtpk(float lo, float hi) {
  unsigned int r;
  asm("v_cvt_pk_bf16_f32 %0, %1, %2" : "=v"(r) : "v"(lo), "v"(hi));
  return r;
}

// ---------------------------------------------------------------------------
__global__ __launch_bounds__(256) void cvt_f32_bf16(const float* __restrict__ in,
                                                    unsigned short* __restrict__ out) {
  int i = blockIdx.x * 256 + threadIdx.x;
  float4 v = ((const float4*)in)[i];
  out[4 * i + 0] = f2bf(v.x);
  out[4 * i + 1] = f2bf(v.y);
  out[4 * i + 2] = f2bf(v.z);
  out[4 * i + 3] = f2bf(v.w);
}

// 4 weight transposes in one launch: W f32 [k][n] -> WT bf16 [n][k]
__global__ __launch_bounds__(256) void wtrans4(const float* __restrict__ W0,
                                               const float* __restrict__ W1,
                                               const float* __restrict__ W2,
                                               const float* __restrict__ W3,
                                               unsigned short* __restrict__ T0,
                                               unsigned short* __restrict__ T1,
                                               unsigned short* __restrict__ T2,
                                               unsigned short* __restrict__ T3) {
  int z = blockIdx.z;
  const float* W = z == 0 ? W0 : z == 1 ? W1 : z == 2 ? W2 : W3;
  unsigned short* WT = z == 0 ? T0 : z == 1 ? T1 : z == 2 ? T2 : T3;
  __shared__ float T[32][33];
  int k0 = blockIdx.x * 32, n0 = blockIdx.y * 32;
  int c = threadIdx.x & 31, r8 = threadIdx.x >> 5;
#pragma unroll
  for (int it = 0; it < 4; ++it) {
    int rr = r8 + it * 8;
    T[rr][c] = W[(size_t)(k0 + rr) * 1024 + n0 + c];
  }
  __syncthreads();
#pragma unroll
  for (int it = 0; it < 4; ++it) {
    int rr = r8 + it * 8;
    WT[(size_t)(n0 + rr) * 1024 + k0 + c] = f2bf(T[c][rr]);
  }
}

// ---------------------------------------------------------------------------
// LDS-staged MFMA GEMM, BM=BN=BK=64, 4 waves, XOR-swizzled 16B chunks.
// mode 0: bf16 head layout [bh][l][64]
// mode 1: bf16 VT-permuted [bh][64][1024]  (k-order permuted per 32-block)
// mode 2: f32 row-major [m][n]
__global__ __launch_bounds__(256) void gemm_st(const unsigned short* __restrict__ A,
                                               const unsigned short* __restrict__ B0,
                                               const unsigned short* __restrict__ B1,
                                               const unsigned short* __restrict__ B2,
                                               const float* __restrict__ c0,
                                               const float* __restrict__ c1,
                                               const float* __restrict__ c2,
                                               void* __restrict__ Y0,
                                               void* __restrict__ Y1,
                                               void* __restrict__ Y2,
                                               int m0, int m1, int m2) {
  int z = blockIdx.z;
  const unsigned short* BT = z == 0 ? B0 : z == 1 ? B1 : B2;
  const float* bias = z == 0 ? c0 : z == 1 ? c1 : c2;
  void* Y = z == 0 ? Y0 : z == 1 ? Y1 : Y2;
  int mode = z == 0 ? m0 : z == 1 ? m1 : m2;

  __shared__ __align__(16) unsigned short As[64 * 64];
  __shared__ __align__(16) unsigned short Bs[64 * 64];
  int tid = threadIdx.x;
  int w = tid >> 6, l = tid & 63, g = l >> 4, l15 = l & 15;
  int bm = blockIdx.x * 64, bn = blockIdx.y * 64;

  int sr = tid >> 2;
  int sj = (tid & 3) * 2;
  int sw0 = (sj ^ (sr & 7)) * 8;
  int sw1 = ((sj + 1) ^ (sr & 7)) * 8;
  const int arow = w * 16 + l15;

  f32x4 acc[4];
#pragma unroll
  for (int t = 0; t < 4; ++t)
#pragma unroll
    for (int r = 0; r < 4; ++r) acc[t][r] = 0.f;

  for (int k0 = 0; k0 < 1024; k0 += 64) {
    short8 av0 = *(const short8*)&A[(size_t)(bm + sr) * 1024 + k0 + sj * 8];
    short8 av1 = *(const short8*)&A[(size_t)(bm + sr) * 1024 + k0 + sj * 8 + 8];
    short8 bv0 = *(const short8*)&BT[(size_t)(bn + sr) * 1024 + k0 + sj * 8];
    short8 bv1 = *(const short8*)&BT[(size_t)(bn + sr) * 1024 + k0 + sj * 8 + 8];
    __syncthreads();
    *(short8*)&As[sr * 64 + sw0] = av0;
    *(short8*)&As[sr * 64 + sw1] = av1;
    *(short8*)&Bs[sr * 64 + sw0] = bv0;
    *(short8*)&Bs[sr * 64 + sw1] = bv1;
    __syncthreads();
#pragma unroll
    for (int kc = 0; kc < 2; ++kc) {
      short8 a = *(const short8*)&As[arow * 64 + ((kc * 4 + g) ^ (arow & 7)) * 8];
#pragma unroll
      for (int t = 0; t < 4; ++t) {
        int brow = t * 16 + l15;
        short8 b = *(const short8*)&Bs[brow * 64 + ((kc * 4 + g) ^ (brow & 7)) * 8];
        acc[t] = __builtin_amdgcn_mfma_f32_16x16x32_bf16(a, b, acc[t], 0, 0, 0);
      }
    }
  }

#pragma unroll
  for (int t = 0; t < 4; ++t) {
    int n = bn + 16 * t + l15;
    float bv = bias[n];
#pragma unroll
    for (int r = 0; r < 4; ++r) {
      int m = bm + w * 16 + 4 * g + r;
      float v = acc[t][r] + bv;
      if (mode == 0) {
        int b = m >> 10, ll = m & 1023, h = n >> 6, hd = n & 63;
        ((unsigned short*)Y)[(((size_t)(b * 16 + h) * 1024) + ll) * 64 + hd] = f2bf(v);
      } else if (mode == 1) {
        int b = m >> 10, ll = m & 1023, h = n >> 6, hd = n & 63;
        int jp = (ll & ~31) | (((ll >> 2) & 3) * 8 + ((ll >> 4) & 1) * 4 + (ll & 3));
        ((unsigned short*)Y)[(((size_t)(b * 16 + h) * 64) + hd) * 1024 + jp] = f2bf(v);
      } else {
        ((float*)Y)[(size_t)m * 1024 + n] = v;
      }
    }
  }
}

// ---------------------------------------------------------------------------
__global__ __launch_bounds__(256) void sqnorm(const unsigned short* __restrict__ Qb,
                                              const unsigned short* __restrict__ Kb,
                                              float* __restrict__ q2,
                                              float* __restrict__ k2) {
  int row = blockIdx.x * 256 + threadIdx.x;
  const unsigned short* src = blockIdx.y ? Kb : Qb;
  float* dst = blockIdx.y ? k2 : q2;
  const short8* p = (const short8*)&src[(size_t)row * 64];
  float s = 0.f;
#pragma unroll
  for (int c = 0; c < 8; ++c) {
    short8 v = p[c];
#pragma unroll
    for (int e = 0; e < 8; ++e) {
      float f = bf2f((unsigned short)v[e]);
      s = fmaf(f, f, s);
    }
  }
  dst[row] = s;
}

// SoA score chain for 8 values: s_i = (1+sqrt(d2_i)/64)^-65.5 * rn_i
__device__ inline void score8(const float* dot, const float* sq, const float* rn,
                              float* out) {
  float d2[8], gg[8], lg[8];
#pragma unroll
  for (int i = 0; i < 8; ++i) d2[i] = fmaxf(fmaf(-2.f, dot[i], sq[i]), 1e-12f);
#pragma unroll
  for (int i = 0; i < 8; ++i) gg[i] = __builtin_amdgcn_sqrtf(d2[i]) * 0.015625f;
#pragma unroll
  for (int i = 0; i < 8; ++i) lg[i] = __builtin_amdgcn_logf(1.f + gg[i]);
#pragma unroll
  for (int i = 0; i < 8; ++i)
    out[i] = __builtin_amdgcn_exp2f(-65.5f * lg[i]) * rn[i];
}

// ---------------------------------------------------------------------------
// Pass A: column sums -> rnc = colsum^-0.5.
// grid (32 bh, 16 jt64); 512 thr. Wave w: cols jt*64+(w&3)*16, i-half (w>>2).
// Software-pipelined: next iteration's Q prefetched into rotating registers.
__global__ __launch_bounds__(512, 4) void colsum_mfma(const unsigned short* __restrict__ Qb,
                                                      const unsigned short* __restrict__ Kb,
                                                      const float* __restrict__ q2,
                                                      const float* __restrict__ k2,
                                                      float* __restrict__ rnc) {
  __shared__ float red[8][16];
  int bh = blockIdx.x, jt = blockIdx.y;
  int tid = threadIdx.x, w = tid >> 6, l = tid & 63;
  int g = l >> 4, l15 = l & 15;
  int wq = w & 3, wj = w >> 2;
  const unsigned short* Qp = Qb + (size_t)bh * 65536;
  const unsigned short* Kp = Kb + (size_t)bh * 65536;
  const float* q2p = q2 + (size_t)bh * 1024;
  int j = jt * 64 + wq * 16 + l15;

  short8 bk0 = *(const short8*)&Kp[(size_t)j * 64 + 8 * g];
  short8 bk1 = *(const short8*)&Kp[(size_t)j * 64 + 32 + 8 * g];
  float k2j = k2[(size_t)bh * 1024 + j];
  float colacc = 0.f;

  const int ibase = wj * 512;
  short8 a0 = *(const short8*)&Qp[(size_t)(ibase + l15) * 64 + 8 * g];
  short8 a1 = *(const short8*)&Qp[(size_t)(ibase + l15) * 64 + 32 + 8 * g];
  short8 a2 = *(const short8*)&Qp[(size_t)(ibase + 16 + l15) * 64 + 8 * g];
  short8 a3 = *(const short8*)&Qp[(size_t)(ibase + 16 + l15) * 64 + 32 + 8 * g];

#pragma unroll 2
  for (int s = 0; s < 16; ++s) {
    int i0 = ibase + s * 32;
    int in = ibase + ((s + 1) & 15) * 32;
    // prefetch next iteration's Q
    short8 n0 = *(const short8*)&Qp[(size_t)(in + l15) * 64 + 8 * g];
    short8 n1 = *(const short8*)&Qp[(size_t)(in + l15) * 64 + 32 + 8 * g];
    short8 n2 = *(const short8*)&Qp[(size_t)(in + 16 + l15) * 64 + 8 * g];
    short8 n3 = *(const short8*)&Qp[(size_t)(in + 16 + l15) * 64 + 32 + 8 * g];
    float4 qv = *(const float4*)&q2p[i0 + 4 * g];
    float4 qv2 = *(const float4*)&q2p[i0 + 16 + 4 * g];

    f32x4 ca, cb;
#pragma unroll
    for (int r = 0; r < 4; ++r) { ca[r] = 0.f; cb[r] = 0.f; }
    ca = __builtin_amdgcn_mfma_f32_16x16x32_bf16(a0, bk0, ca, 0, 0, 0);
    ca = __builtin_amdgcn_mfma_f32_16x16x32_bf16(a1, bk1, ca, 0, 0, 0);
    cb = __builtin_amdgcn_mfma_f32_16x16x32_bf16(a2, bk0, cb, 0, 0, 0);
    cb = __builtin_amdgcn_mfma_f32_16x16x32_bf16(a3, bk1, cb, 0, 0, 0);

    float dot[8] = {ca[0], ca[1], ca[2], ca[3], cb[0], cb[1], cb[2], cb[3]};
    float sq[8] = {qv.x + k2j, qv.y + k2j, qv.z + k2j, qv.w + k2j,
                   qv2.x + k2j, qv2.y + k2j, qv2.z + k2j, qv2.w + k2j};
    float rn[8] = {1.f, 1.f, 1.f, 1.f, 1.f, 1.f, 1.f, 1.f};
    float sc[8];
    score8(dot, sq, rn, sc);
    colacc += ((sc[0] + sc[1]) + (sc[2] + sc[3])) + ((sc[4] + sc[5]) + (sc[6] + sc[7]));

    a0 = n0; a1 = n1; a2 = n2; a3 = n3;
  }
  colacc += __shfl_xor(colacc, 16);
  colacc += __shfl_xor(colacc, 32);
  if (l < 16) red[w][l] = colacc;
  __syncthreads();
  if (tid < 64) {
    float s = red[tid >> 4][tid & 15] + red[(tid >> 4) + 4][tid & 15];
    rnc[(size_t)bh * 1024 + jt * 64 + tid] = __builtin_amdgcn_rsqf(s);
  }
}

// ---------------------------------------------------------------------------
// Pass B (swapped QK, register-resident P): grid (32 bh, 16 it64); 512 thr.
// Wave w: q-subtile (w&3), j-half (w>>2). Software-pipelined K; early V loads.
__global__ __launch_bounds__(512, 4) void attn_mfma(const unsigned short* __restrict__ Qb,
                                                    const unsigned short* __restrict__ Kb,
                                                    const unsigned short* __restrict__ VTp,
                                                    const float* __restrict__ q2,
                                                    const float* __restrict__ k2,
                                                    const float* __restrict__ rnc,
                                                    unsigned short* __restrict__ AO) {
  __shared__ float Ls[8][64][17];
  __shared__ float Ds[8][16];
  int bh = blockIdx.x;
  int tid = threadIdx.x, w = tid >> 6, l = tid & 63;
  int g = l >> 4, l15 = l & 15;
  int wq = w & 3, wj = w >> 2;
  int it0 = blockIdx.y * 64 + wq * 16;
  const unsigned short* Qp = Qb + (size_t)bh * 65536;
  const unsigned short* Kp = Kb + (size_t)bh * 65536;
  const unsigned short* Vp = VTp + (size_t)bh * 65536;
  const float* k2p = k2 + (size_t)bh * 1024;
  const float* rnp = rnc + (size_t)bh * 1024;
  int b = bh >> 4, h = bh & 15;

  // Q as B-operand (n = q-row), fixed for the whole kernel
  short8 bq0 = *(const short8*)&Qp[(size_t)(it0 + l15) * 64 + 8 * g];
  short8 bq1 = *(const short8*)&Qp[(size_t)(it0 + l15) * 64 + 32 + 8 * g];
  float q2l = q2[(size_t)bh * 1024 + it0 + l15];

  f32x4 o[4];
#pragma unroll
  for (int t = 0; t < 4; ++t)
#pragma unroll
    for (int r = 0; r < 4; ++r) o[t][r] = 0.f;
  float dacc = 0.f;

  const int jbase = wj * 512;
  // prefetch iteration 0's K
  short8 kA0 = *(const short8*)&Kp[(size_t)(jbase + l15) * 64 + 8 * g];
  short8 kA1 = *(const short8*)&Kp[(size_t)(jbase + l15) * 64 + 32 + 8 * g];
  short8 kB0 = *(const short8*)&Kp[(size_t)(jbase + 16 + l15) * 64 + 8 * g];
  short8 kB1 = *(const short8*)&Kp[(size_t)(jbase + 16 + l15) * 64 + 32 + 8 * g];

#pragma unroll 2
  for (int c = 0; c < 16; ++c) {
    int j0 = jbase + c * 32;
    int jn = jbase + ((c + 1) & 15) * 32;
    // V loads for current iter (independent of score results)
    short8 v0 = *(const short8*)&Vp[(size_t)(0 + l15) * 1024 + j0 + 8 * g];
    short8 v1 = *(const short8*)&Vp[(size_t)(16 + l15) * 1024 + j0 + 8 * g];
    short8 v2 = *(const short8*)&Vp[(size_t)(32 + l15) * 1024 + j0 + 8 * g];
    short8 v3 = *(const short8*)&Vp[(size_t)(48 + l15) * 1024 + j0 + 8 * g];
    // next-iteration K prefetch (rotating registers)
    short8 nA0 = *(const short8*)&Kp[(size_t)(jn + l15) * 64 + 8 * g];
    short8 nA1 = *(const short8*)&Kp[(size_t)(jn + l15) * 64 + 32 + 8 * g];
    short8 nB0 = *(const short8*)&Kp[(size_t)(jn + 16 + l15) * 64 + 8 * g];
    short8 nB1 = *(const short8*)&Kp[(size_t)(jn + 16 + l15) * 64 + 32 + 8 * g];

    float4 k20 = *(const float4*)&k2p[j0 + 4 * g];
    float4 rn0 = *(const float4*)&rnp[j0 + 4 * g];
    float4 k21 = *(const float4*)&k2p[j0 + 16 + 4 * g];
    float4 rn1 = *(const float4*)&rnp[j0 + 16 + 4 * g];

    f32x4 c0, c1;
#pragma unroll
    for (int r = 0; r < 4; ++r) { c0[r] = 0.f; c1[r] = 0.f; }
    c0 = __builtin_amdgcn_mfma_f32_16x16x32_bf16(kA0, bq0, c0, 0, 0, 0);
    c0 = __builtin_amdgcn_mfma_f32_16x16x32_bf16(kA1, bq1, c0, 0, 0, 0);
    c1 = __builtin_amdgcn_mfma_f32_16x16x32_bf16(kB0, bq0, c1, 0, 0, 0);
    c1 = __builtin_amdgcn_mfma_f32_16x16x32_bf16(kB1, bq1, c1, 0, 0, 0);

    float dot[8] = {c0[0], c0[1], c0[2], c0[3], c1[0], c1[1], c1[2], c1[3]};
    float sq[8] = {q2l + k20.x, q2l + k20.y, q2l + k20.z, q2l + k20.w,
                   q2l + k21.x, q2l + k21.y, q2l + k21.z, q2l + k21.w};
    float rn[8] = {rn0.x, rn0.y, rn0.z, rn0.w, rn1.x, rn1.y, rn1.z, rn1.w};
    float sc[8];
    score8(dot, sq, rn, sc);
    dacc += ((sc[0] + sc[1]) + (sc[2] + sc[3])) + ((sc[4] + sc[5]) + (sc[6] + sc[7]));

    int pi[4];
    pi[0] = (int)cvtpk(sc[0], sc[1]);
    pi[1] = (int)cvtpk(sc[2], sc[3]);
    pi[2] = (int)cvtpk(sc[4], sc[5]);
    pi[3] = (int)cvtpk(sc[6], sc[7]);
    short8 pa = *(short8*)pi;

    o[0] = __builtin_amdgcn_mfma_f32_16x16x32_bf16(pa, v0, o[0], 0, 0, 0);
    o[1] = __builtin_amdgcn_mfma_f32_16x16x32_bf16(pa, v1, o[1], 0, 0, 0);
    o[2] = __builtin_amdgcn_mfma_f32_16x16x32_bf16(pa, v2, o[2], 0, 0, 0);
    o[3] = __builtin_amdgcn_mfma_f32_16x16x32_bf16(pa, v3, o[3], 0, 0, 0);

    kA0 = nA0; kA1 = nA1; kB0 = nB0; kB1 = nB1;
  }

  // per-row partial sums over this wave's j-half
  dacc += __shfl_xor(dacc, 16);
  dacc += __shfl_xor(dacc, 32);
  if (l < 16) Ds[w][l] = dacc;
#pragma unroll
  for (int t = 0; t < 4; ++t)
#pragma unroll
    for (int r = 0; r < 4; ++r) Ls[w][l][t * 4 + r] = o[t][r];
  __syncthreads();

  // lower wave of each (wq) pair merges the two j-halves and writes
  if (w < 4) {
#pragma unroll
    for (int t = 0; t < 4; ++t) {
#pragma unroll
      for (int r = 0; r < 4; ++r) {
        float ov = o[t][r] + Ls[w + 4][l][t * 4 + r];
        float dv = Ds[w][4 * g + r] + Ds[w + 4][4 * g + r];
        int m = b * 1024 + it0 + 4 * g + r;
        int n = h * 64 + t * 16 + l15;
        AO[(size_t)m * 1024 + n] = f2bf(ov / dv);
      }
    }
  }
}

// ---------------------------------------------------------------------------
extern "C" void kernel_launch(void* const* d_in, const int* in_sizes, int n_in,
                              void* d_out, int out_size, void* d_ws, size_t ws_size,
                              hipStream_t stream) {
  const float* x  = (const float*)d_in[0];
  const float* WQ = (const float*)d_in[1];
  const float* bQ = (const float*)d_in[2];
  const float* WK = (const float*)d_in[3];
  const float* bK = (const float*)d_in[4];
  const float* WV = (const float*)d_in[5];
  const float* bV = (const float*)d_in[6];
  const float* WO = (const float*)d_in[7];
  const float* bO = (const float*)d_in[8];

  char* base = (char*)d_ws;
  unsigned short* xb  = (unsigned short*)(base);
  unsigned short* WQT = (unsigned short*)(base + (4u  << 20));
  unsigned short* WKT = (unsigned short*)(base + (6u  << 20));
  unsigned short* WVT = (unsigned short*)(base + (8u  << 20));
  unsigned short* WOT = (unsigned short*)(base + (10u << 20));
  unsigned short* Qb  = (unsigned short*)(base + (12u << 20));
  unsigned short* Kb  = (unsigned short*)(base + (16u << 20));
  unsigned short* VTp = (unsigned short*)(base + (20u << 20));
  unsigned short* AOb = (unsigned short*)(base + (24u << 20));
  float* q2  = (float*)(base + (28u << 20));
  float* k2  = (float*)(base + (28u << 20) + (128u << 10));
  float* rnc = (float*)(base + (28u << 20) + (256u << 10));

  cvt_f32_bf16<<<2048, 256, 0, stream>>>(x, xb);
  wtrans4<<<dim3(32, 32, 4), 256, 0, stream>>>(WQ, WK, WV, WO, WQT, WKT, WVT, WOT);

  // fused Q,K,V projections (V written k-permuted-transposed)
  gemm_st<<<dim3(32, 16, 3), 256, 0, stream>>>(xb, WQT, WKT, WVT, bQ, bK, bV,
                                               Qb, Kb, VTp, 0, 0, 1);

  sqnorm<<<dim3(128, 2), 256, 0, stream>>>(Qb, Kb, q2, k2);
  colsum_mfma<<<dim3(32, 16), 512, 0, stream>>>(Qb, Kb, q2, k2, rnc);
  attn_mfma<<<dim3(32, 16), 512, 0, stream>>>(Qb, Kb, VTp, q2, k2, rnc, AOb);

  // output projection
  gemm_st<<<dim3(32, 16, 1), 256, 0, stream>>>(AOb, WOT, WOT, WOT, bO, bO, bO,
                                               d_out, d_out, d_out, 2, 2, 2);
}

// Round 7
// 121.624 us; speedup vs baseline: 1.3179x; 1.3179x over previous
//
#include <hip/hip_runtime.h>
#include <math.h>

// B=2, L=1024, D=1024, H=16, HD=64.
// probs_ij = s_ij*nc_j^-0.5 / sum_j(s_ij*nc_j^-0.5)   (N_R^-0.5 cancels)
// s_ij = (1 + dist_ij/64)^(-65.5), dist from bf16-rounded Q,K.

typedef __attribute__((ext_vector_type(8))) short short8;
typedef __attribute__((ext_vector_type(4))) float f32x4;

__device__ inline unsigned short f2bf(float f) {
  unsigned int u = __float_as_uint(f);
  unsigned int r = (u + 0x7FFFu + ((u >> 16) & 1u)) >> 16;
  return (unsigned short)r;
}
__device__ inline float bf2f(unsigned short s) {
  return __uint_as_float(((unsigned int)s) << 16);
}
__device__ inline float score_fn(float dot, float sq) {
  float d2 = fmaxf(fmaf(-2.f, dot, sq), 1e-12f);
  float sd = __builtin_amdgcn_sqrtf(d2);
  float lg = __builtin_amdgcn_logf(fmaf(sd, 0.015625f, 1.0f));  // log2(1+dist/64)
  return __builtin_amdgcn_exp2f(-65.5f * lg);
}
// pack two f32 -> one dword of 2 bf16 (RNE), lo = first arg
__device__ inline unsigned int cvtpk(float lo, float hi) {
  unsigned int r;
  asm("v_cvt_pk_bf16_f32 %0, %1, %2" : "=v"(r) : "v"(lo), "v"(hi));
  return r;
}
// async global->LDS 16B/lane; dest must be linear (base + lane*16)
#define GLD16(lptr, gptr)                                                      \
  __builtin_amdgcn_global_load_lds(                                            \
      (const __attribute__((address_space(1))) void*)(gptr),                   \
      (__attribute__((address_space(3))) void*)(lptr), 16, 0, 0)

// ---------------------------------------------------------------------------
__global__ __launch_bounds__(256) void cvt_f32_bf16(const float* __restrict__ in,
                                                    unsigned short* __restrict__ out) {
  int i = blockIdx.x * 256 + threadIdx.x;
  float4 v = ((const float4*)in)[i];
  out[4 * i + 0] = f2bf(v.x);
  out[4 * i + 1] = f2bf(v.y);
  out[4 * i + 2] = f2bf(v.z);
  out[4 * i + 3] = f2bf(v.w);
}

// 4 weight transposes in one launch: W f32 [k][n] -> WT bf16 [n][k]
__global__ __launch_bounds__(256) void wtrans4(const float* __restrict__ W0,
                                               const float* __restrict__ W1,
                                               const float* __restrict__ W2,
                                               const float* __restrict__ W3,
                                               unsigned short* __restrict__ T0,
                                               unsigned short* __restrict__ T1,
                                               unsigned short* __restrict__ T2,
                                               unsigned short* __restrict__ T3) {
  int z = blockIdx.z;
  const float* W = z == 0 ? W0 : z == 1 ? W1 : z == 2 ? W2 : W3;
  unsigned short* WT = z == 0 ? T0 : z == 1 ? T1 : z == 2 ? T2 : T3;
  __shared__ float T[32][33];
  int k0 = blockIdx.x * 32, n0 = blockIdx.y * 32;
  int c = threadIdx.x & 31, r8 = threadIdx.x >> 5;
#pragma unroll
  for (int it = 0; it < 4; ++it) {
    int rr = r8 + it * 8;
    T[rr][c] = W[(size_t)(k0 + rr) * 1024 + n0 + c];
  }
  __syncthreads();
#pragma unroll
  for (int it = 0; it < 4; ++it) {
    int rr = r8 + it * 8;
    WT[(size_t)(n0 + rr) * 1024 + k0 + c] = f2bf(T[c][rr]);
  }
}

// ---------------------------------------------------------------------------
// MFMA GEMM, BM=BN=BK=64, 4 waves; global_load_lds double-buffered staging.
// Source pre-swizzled (chunk ^= row&7), ds_read applies same XOR.
// mode 0: bf16 head layout; 1: bf16 VT-permuted; 2: f32 row-major
__global__ __launch_bounds__(256) void gemm_st(const unsigned short* __restrict__ A,
                                               const unsigned short* __restrict__ B0,
                                               const unsigned short* __restrict__ B1,
                                               const unsigned short* __restrict__ B2,
                                               const float* __restrict__ c0,
                                               const float* __restrict__ c1,
                                               const float* __restrict__ c2,
                                               void* __restrict__ Y0,
                                               void* __restrict__ Y1,
                                               void* __restrict__ Y2,
                                               int m0, int m1, int m2) {
  int z = blockIdx.z;
  const unsigned short* BT = z == 0 ? B0 : z == 1 ? B1 : B2;
  const float* bias = z == 0 ? c0 : z == 1 ? c1 : c2;
  void* Y = z == 0 ? Y0 : z == 1 ? Y1 : Y2;
  int mode = z == 0 ? m0 : z == 1 ? m1 : m2;

  __shared__ __align__(16) unsigned short As[2][64 * 64];
  __shared__ __align__(16) unsigned short Bs[2][64 * 64];
  int tid = threadIdx.x;
  int w = tid >> 6, l = tid & 63, g = l >> 4, l15 = l & 15;
  int bm = blockIdx.x * 64, bn = blockIdx.y * 64;
  const int arow = w * 16 + l15;
  const int x7 = l15 & 7;

  // staging geometry: 512 chunks of 16B per 8KB tile, 2 per thread
  const int i0s = tid, i1s = 256 + tid;
  const int r0 = i0s >> 3, s0 = (i0s & 7) ^ (r0 & 7);
  const int r1 = i1s >> 3, s1 = (i1s & 7) ^ (r1 & 7);

  // prologue: stage k-tile 0
  GLD16(&As[0][i0s * 8], &A[(size_t)(bm + r0) * 1024 + s0 * 8]);
  GLD16(&As[0][i1s * 8], &A[(size_t)(bm + r1) * 1024 + s1 * 8]);
  GLD16(&Bs[0][i0s * 8], &BT[(size_t)(bn + r0) * 1024 + s0 * 8]);
  GLD16(&Bs[0][i1s * 8], &BT[(size_t)(bn + r1) * 1024 + s1 * 8]);

  f32x4 acc[4];
#pragma unroll
  for (int t = 0; t < 4; ++t)
#pragma unroll
    for (int r = 0; r < 4; ++r) acc[t][r] = 0.f;

  __syncthreads();
  for (int t = 0; t < 16; ++t) {
    int cur = t & 1;
    if (t < 15) {
      int kn = (t + 1) * 64;
      GLD16(&As[cur ^ 1][i0s * 8], &A[(size_t)(bm + r0) * 1024 + kn + s0 * 8]);
      GLD16(&As[cur ^ 1][i1s * 8], &A[(size_t)(bm + r1) * 1024 + kn + s1 * 8]);
      GLD16(&Bs[cur ^ 1][i0s * 8], &BT[(size_t)(bn + r0) * 1024 + kn + s0 * 8]);
      GLD16(&Bs[cur ^ 1][i1s * 8], &BT[(size_t)(bn + r1) * 1024 + kn + s1 * 8]);
    }
#pragma unroll
    for (int kc = 0; kc < 2; ++kc) {
      short8 a = *(const short8*)&As[cur][arow * 64 + ((kc * 4 + g) ^ x7) * 8];
#pragma unroll
      for (int tt = 0; tt < 4; ++tt) {
        short8 b = *(const short8*)&Bs[cur][(tt * 16 + l15) * 64 + ((kc * 4 + g) ^ x7) * 8];
        acc[tt] = __builtin_amdgcn_mfma_f32_16x16x32_bf16(a, b, acc[tt], 0, 0, 0);
      }
    }
    __syncthreads();
  }

#pragma unroll
  for (int t = 0; t < 4; ++t) {
    int n = bn + 16 * t + l15;
    float bv = bias[n];
#pragma unroll
    for (int r = 0; r < 4; ++r) {
      int m = bm + w * 16 + 4 * g + r;
      float v = acc[t][r] + bv;
      if (mode == 0) {
        int b = m >> 10, ll = m & 1023, h = n >> 6, hd = n & 63;
        ((unsigned short*)Y)[(((size_t)(b * 16 + h) * 1024) + ll) * 64 + hd] = f2bf(v);
      } else if (mode == 1) {
        int b = m >> 10, ll = m & 1023, h = n >> 6, hd = n & 63;
        int jp = (ll & ~31) | (((ll >> 2) & 3) * 8 + ((ll >> 4) & 1) * 4 + (ll & 3));
        ((unsigned short*)Y)[(((size_t)(b * 16 + h) * 64) + hd) * 1024 + jp] = f2bf(v);
      } else {
        ((float*)Y)[(size_t)m * 1024 + n] = v;
      }
    }
  }
}

// ---------------------------------------------------------------------------
__global__ __launch_bounds__(256) void sqnorm(const unsigned short* __restrict__ Qb,
                                              const unsigned short* __restrict__ Kb,
                                              float* __restrict__ q2,
                                              float* __restrict__ k2) {
  int row = blockIdx.x * 256 + threadIdx.x;
  const unsigned short* src = blockIdx.y ? Kb : Qb;
  float* dst = blockIdx.y ? k2 : q2;
  const short8* p = (const short8*)&src[(size_t)row * 64];
  float s = 0.f;
#pragma unroll
  for (int c = 0; c < 8; ++c) {
    short8 v = p[c];
#pragma unroll
    for (int e = 0; e < 8; ++e) {
      float f = bf2f((unsigned short)v[e]);
      s = fmaf(f, f, s);
    }
  }
  dst[row] = s;
}

// ---------------------------------------------------------------------------
// Pass A: column sums -> rnc = colsum^-0.5.
// grid (32 bh, 16 jt64), 256 thr. Wave w owns cols jt*64+w*16..+15 (K frags in
// regs); Q streamed in 16 tiles of 64 rows via LDS (2-phase, gload_lds).
__global__ __launch_bounds__(256) void colsum_mfma(const unsigned short* __restrict__ Qb,
                                                   const unsigned short* __restrict__ Kb,
                                                   const float* __restrict__ q2,
                                                   const float* __restrict__ k2,
                                                   float* __restrict__ rnc) {
  __shared__ __align__(16) unsigned short Qd[2][64 * 64];
  __shared__ __align__(16) float q2s[1024];
  int bh = blockIdx.x, jt = blockIdx.y;
  int tid = threadIdx.x, w = tid >> 6, l = tid & 63;
  int g = l >> 4, l15 = l & 15;
  const int x7 = l15 & 7;
  const unsigned short* Qp = Qb + (size_t)bh * 65536;
  const unsigned short* Kp = Kb + (size_t)bh * 65536;
  int j = jt * 64 + w * 16 + l15;

  const int i0s = tid, i1s = 256 + tid;
  const int r0 = i0s >> 3, s0 = (i0s & 7) ^ (r0 & 7);
  const int r1 = i1s >> 3, s1 = (i1s & 7) ^ (r1 & 7);

  GLD16(&q2s[tid * 4], q2 + (size_t)bh * 1024 + tid * 4);
  GLD16(&Qd[0][i0s * 8], Qp + (size_t)r0 * 64 + s0 * 8);
  GLD16(&Qd[0][i1s * 8], Qp + (size_t)r1 * 64 + s1 * 8);

  short8 bk0 = *(const short8*)&Kp[(size_t)j * 64 + 8 * g];
  short8 bk1 = *(const short8*)&Kp[(size_t)j * 64 + 32 + 8 * g];
  float k2j = k2[(size_t)bh * 1024 + j];
  float colacc = 0.f;

  __syncthreads();
  for (int t = 0; t < 16; ++t) {
    int cur = t & 1;
    if (t < 15) {
      int inx = (t + 1) * 64;
      GLD16(&Qd[cur ^ 1][i0s * 8], Qp + (size_t)(inx + r0) * 64 + s0 * 8);
      GLD16(&Qd[cur ^ 1][i1s * 8], Qp + (size_t)(inx + r1) * 64 + s1 * 8);
    }
    const unsigned short* Ql = Qd[cur];
#pragma unroll
    for (int tp = 0; tp < 4; ++tp) {
      int rowb = (16 * tp + l15) * 64;
      short8 a0 = *(const short8*)&Ql[rowb + ((g) ^ x7) * 8];
      short8 a1 = *(const short8*)&Ql[rowb + ((4 + g) ^ x7) * 8];
      f32x4 cf;
#pragma unroll
      for (int r = 0; r < 4; ++r) cf[r] = 0.f;
      cf = __builtin_amdgcn_mfma_f32_16x16x32_bf16(a0, bk0, cf, 0, 0, 0);
      cf = __builtin_amdgcn_mfma_f32_16x16x32_bf16(a1, bk1, cf, 0, 0, 0);
      float4 qv = *(const float4*)&q2s[t * 64 + 16 * tp + 4 * g];
      colacc += score_fn(cf[0], qv.x + k2j);
      colacc += score_fn(cf[1], qv.y + k2j);
      colacc += score_fn(cf[2], qv.z + k2j);
      colacc += score_fn(cf[3], qv.w + k2j);
    }
    __syncthreads();
  }
  colacc += __shfl_xor(colacc, 16);
  colacc += __shfl_xor(colacc, 32);
  if (l < 16) rnc[(size_t)bh * 1024 + jt * 64 + w * 16 + l] = __builtin_amdgcn_rsqf(colacc);
}

// ---------------------------------------------------------------------------
// Pass B (swapped QK, register-resident P): grid (32 bh, 16 qt64), 256 thr.
// Wave w owns q-rows qt*64+w*16..+15 (Q frags in regs); K,V streamed in 16
// tiles of 64 cols via LDS (2-phase, gload_lds); k2/rnc staged once.
__global__ __launch_bounds__(256) void attn_mfma(const unsigned short* __restrict__ Qb,
                                                 const unsigned short* __restrict__ Kb,
                                                 const unsigned short* __restrict__ VTp,
                                                 const float* __restrict__ q2,
                                                 const float* __restrict__ k2,
                                                 const float* __restrict__ rnc,
                                                 unsigned short* __restrict__ AO) {
  __shared__ __align__(16) unsigned short Kd[2][64 * 64];
  __shared__ __align__(16) unsigned short Vd[2][64 * 64];
  __shared__ __align__(16) float k2s[1024];
  __shared__ __align__(16) float rns[1024];
  int bh = blockIdx.x;
  int tid = threadIdx.x, w = tid >> 6, l = tid & 63;
  int g = l >> 4, l15 = l & 15;
  const int x7 = l15 & 7;
  int it0 = blockIdx.y * 64 + w * 16;
  const unsigned short* Qp = Qb + (size_t)bh * 65536;
  const unsigned short* Kp = Kb + (size_t)bh * 65536;
  const unsigned short* Vp = VTp + (size_t)bh * 65536;
  int b = bh >> 4, h = bh & 15;

  const int i0s = tid, i1s = 256 + tid;
  const int r0 = i0s >> 3, s0 = (i0s & 7) ^ (r0 & 7);
  const int r1 = i1s >> 3, s1 = (i1s & 7) ^ (r1 & 7);

  // stage k2/rnc (once) + K/V tile 0
  GLD16(&k2s[tid * 4], k2 + (size_t)bh * 1024 + tid * 4);
  GLD16(&rns[tid * 4], rnc + (size_t)bh * 1024 + tid * 4);
  GLD16(&Kd[0][i0s * 8], Kp + (size_t)r0 * 64 + s0 * 8);
  GLD16(&Kd[0][i1s * 8], Kp + (size_t)r1 * 64 + s1 * 8);
  GLD16(&Vd[0][i0s * 8], Vp + (size_t)r0 * 1024 + s0 * 8);
  GLD16(&Vd[0][i1s * 8], Vp + (size_t)r1 * 1024 + s1 * 8);

  // Q as B-operand (n = q-row), fixed for the whole kernel
  short8 bq0 = *(const short8*)&Qp[(size_t)(it0 + l15) * 64 + 8 * g];
  short8 bq1 = *(const short8*)&Qp[(size_t)(it0 + l15) * 64 + 32 + 8 * g];
  float q2l = q2[(size_t)bh * 1024 + it0 + l15];

  f32x4 o[4];
#pragma unroll
  for (int t = 0; t < 4; ++t)
#pragma unroll
    for (int r = 0; r < 4; ++r) o[t][r] = 0.f;
  float dacc = 0.f;

  __syncthreads();
  for (int t = 0; t < 16; ++t) {
    int cur = t & 1;
    if (t < 15) {
      int j0n = (t + 1) * 64;
      GLD16(&Kd[cur ^ 1][i0s * 8], Kp + (size_t)(j0n + r0) * 64 + s0 * 8);
      GLD16(&Kd[cur ^ 1][i1s * 8], Kp + (size_t)(j0n + r1) * 64 + s1 * 8);
      GLD16(&Vd[cur ^ 1][i0s * 8], Vp + (size_t)r0 * 1024 + j0n + s0 * 8);
      GLD16(&Vd[cur ^ 1][i1s * 8], Vp + (size_t)r1 * 1024 + j0n + s1 * 8);
    }
    const unsigned short* Kl = Kd[cur];
    const unsigned short* Vl = Vd[cur];
    int j0 = t * 64;
    float sc[16];
#pragma unroll
    for (int tp = 0; tp < 4; ++tp) {
      int rowb = (16 * tp + l15) * 64;
      short8 a0 = *(const short8*)&Kl[rowb + ((g) ^ x7) * 8];
      short8 a1 = *(const short8*)&Kl[rowb + ((4 + g) ^ x7) * 8];
      f32x4 cf;
#pragma unroll
      for (int r = 0; r < 4; ++r) cf[r] = 0.f;
      cf = __builtin_amdgcn_mfma_f32_16x16x32_bf16(a0, bq0, cf, 0, 0, 0);
      cf = __builtin_amdgcn_mfma_f32_16x16x32_bf16(a1, bq1, cf, 0, 0, 0);
      float4 kv = *(const float4*)&k2s[j0 + 16 * tp + 4 * g];
      float4 rv = *(const float4*)&rns[j0 + 16 * tp + 4 * g];
      sc[tp * 4 + 0] = score_fn(cf[0], q2l + kv.x) * rv.x;
      sc[tp * 4 + 1] = score_fn(cf[1], q2l + kv.y) * rv.y;
      sc[tp * 4 + 2] = score_fn(cf[2], q2l + kv.z) * rv.z;
      sc[tp * 4 + 3] = score_fn(cf[3], q2l + kv.w) * rv.w;
    }
#pragma unroll
    for (int i = 0; i < 16; ++i) dacc += sc[i];
    int pi0[4], pi1[4];
    pi0[0] = (int)cvtpk(sc[0], sc[1]);
    pi0[1] = (int)cvtpk(sc[2], sc[3]);
    pi0[2] = (int)cvtpk(sc[4], sc[5]);
    pi0[3] = (int)cvtpk(sc[6], sc[7]);
    pi1[0] = (int)cvtpk(sc[8], sc[9]);
    pi1[1] = (int)cvtpk(sc[10], sc[11]);
    pi1[2] = (int)cvtpk(sc[12], sc[13]);
    pi1[3] = (int)cvtpk(sc[14], sc[15]);
    short8 pa0 = *(short8*)pi0;
    short8 pa1 = *(short8*)pi1;
#pragma unroll
    for (int tt = 0; tt < 4; ++tt) {
      int rowb = (16 * tt + l15) * 64;
      short8 v0 = *(const short8*)&Vl[rowb + ((g) ^ x7) * 8];
      short8 v1 = *(const short8*)&Vl[rowb + ((4 + g) ^ x7) * 8];
      o[tt] = __builtin_amdgcn_mfma_f32_16x16x32_bf16(pa0, v0, o[tt], 0, 0, 0);
      o[tt] = __builtin_amdgcn_mfma_f32_16x16x32_bf16(pa1, v1, o[tt], 0, 0, 0);
    }
    __syncthreads();
  }

  // full row sums (each wave saw all j): reduce over g-groups, redistribute
  dacc += __shfl_xor(dacc, 16);
  dacc += __shfl_xor(dacc, 32);
  float dv[4];
#pragma unroll
  for (int r = 0; r < 4; ++r) dv[r] = __shfl(dacc, 4 * g + r);

#pragma unroll
  for (int t = 0; t < 4; ++t) {
#pragma unroll
    for (int r = 0; r < 4; ++r) {
      int m = b * 1024 + it0 + 4 * g + r;
      int n = h * 64 + t * 16 + l15;
      AO[(size_t)m * 1024 + n] = f2bf(o[t][r] / dv[r]);
    }
  }
}

// ---------------------------------------------------------------------------
extern "C" void kernel_launch(void* const* d_in, const int* in_sizes, int n_in,
                              void* d_out, int out_size, void* d_ws, size_t ws_size,
                              hipStream_t stream) {
  const float* x  = (const float*)d_in[0];
  const float* WQ = (const float*)d_in[1];
  const float* bQ = (const float*)d_in[2];
  const float* WK = (const float*)d_in[3];
  const float* bK = (const float*)d_in[4];
  const float* WV = (const float*)d_in[5];
  const float* bV = (const float*)d_in[6];
  const float* WO = (const float*)d_in[7];
  const float* bO = (const float*)d_in[8];

  char* base = (char*)d_ws;
  unsigned short* xb  = (unsigned short*)(base);
  unsigned short* WQT = (unsigned short*)(base + (4u  << 20));
  unsigned short* WKT = (unsigned short*)(base + (6u  << 20));
  unsigned short* WVT = (unsigned short*)(base + (8u  << 20));
  unsigned short* WOT = (unsigned short*)(base + (10u << 20));
  unsigned short* Qb  = (unsigned short*)(base + (12u << 20));
  unsigned short* Kb  = (unsigned short*)(base + (16u << 20));
  unsigned short* VTp = (unsigned short*)(base + (20u << 20));
  unsigned short* AOb = (unsigned short*)(base + (24u << 20));
  float* q2  = (float*)(base + (28u << 20));
  float* k2  = (float*)(base + (28u << 20) + (128u << 10));
  float* rnc = (float*)(base + (28u << 20) + (256u << 10));

  cvt_f32_bf16<<<2048, 256, 0, stream>>>(x, xb);
  wtrans4<<<dim3(32, 32, 4), 256, 0, stream>>>(WQ, WK, WV, WO, WQT, WKT, WVT, WOT);

  // fused Q,K,V projections (V written k-permuted-transposed)
  gemm_st<<<dim3(32, 16, 3), 256, 0, stream>>>(xb, WQT, WKT, WVT, bQ, bK, bV,
                                               Qb, Kb, VTp, 0, 0, 1);

  sqnorm<<<dim3(128, 2), 256, 0, stream>>>(Qb, Kb, q2, k2);
  colsum_mfma<<<dim3(32, 16), 256, 0, stream>>>(Qb, Kb, q2, k2, rnc);
  attn_mfma<<<dim3(32, 16), 256, 0, stream>>>(Qb, Kb, VTp, q2, k2, rnc, AOb);

  // output projection
  gemm_st<<<dim3(32, 16, 1), 256, 0, stream>>>(AOb, WOT, WOT, WOT, bO, bO, bO,
                                               d_out, d_out, d_out, 2, 2, 2);
}